// Round 1
// baseline (778.754 us; speedup 1.0000x reference)
//
#include <hip/hip_runtime.h>
#include <math.h>

#define EPS 1e-3f
// B=4, S=256, D=256, v=128, e=64, c=192, NH=8, DK=8, DV=8

// ws layout (floats):
// 0      : WkE[64*64]   (g_in[128+j]*Wk[128+j][n])
// 4096   : WvE[64*64]
// 8192   : cK[64], 8256: dK[64], 8320: cV[64], 8384: dV[64]
// 8448   : q_s [B*D*64]  (relu(q)/sqrt(8))
// 73984  : Pd  [B*D*64]  (V_dst @ We[128:256])
// 139520 : sv  [B*S]     (sum of V_src row)
// 140544 : ssv [B*S]     (sumsq of V_src row)
// 141568 : Qs_k[B*S*64]
// 207104 : Qs_v[B*S*64]
// 272640 : Ps  [B*S*64]  (V_src @ We[0:128])

__global__ void prep_kernel(const float* __restrict__ Wk, const float* __restrict__ bk,
                            const float* __restrict__ Wv, const float* __restrict__ bv,
                            const float* __restrict__ g_in, const float* __restrict__ b_in,
                            float* __restrict__ ws) {
    int tid = threadIdx.x;
    int g = tid >> 6, n = tid & 63;
    if (g == 0) {
        float c = 0.f, dd = 0.f;
        for (int j = 0; j < 192; j++) { float w = Wk[j * 64 + n]; c += g_in[j] * w; dd += b_in[j] * w; }
        ws[8192 + n] = c; ws[8256 + n] = dd + bk[n];
    } else if (g == 1) {
        float c = 0.f, dd = 0.f;
        for (int j = 0; j < 192; j++) { float w = Wv[j * 64 + n]; c += g_in[j] * w; dd += b_in[j] * w; }
        ws[8320 + n] = c; ws[8384 + n] = dd + bv[n];
    } else if (g == 2) {
        for (int j = 0; j < 64; j++) ws[j * 64 + n] = g_in[128 + j] * Wk[(128 + j) * 64 + n];
    } else {
        for (int j = 0; j < 64; j++) ws[4096 + j * 64 + n] = g_in[128 + j] * Wv[(128 + j) * 64 + n];
    }
}

// one block per (b,d): LN(V_dst) -> q (pre-scaled by 1/sqrt(8)); Pd = V_dst @ We[128:256]
__global__ __launch_bounds__(128) void dst_kernel(const float* __restrict__ V_dst,
                           const float* __restrict__ g_vd, const float* __restrict__ b_vd,
                           const float* __restrict__ Wq, const float* __restrict__ bq,
                           const float* __restrict__ We, float* __restrict__ ws) {
    int blk = blockIdx.x;           // b*256 + d
    int tid = threadIdx.x;          // 128
    __shared__ float row[128], vn[128], rs1[2], rs2[2];
    float x = V_dst[blk * 128 + tid];
    row[tid] = x;
    float s1 = x, s2 = x * x;
    #pragma unroll
    for (int o = 1; o <= 32; o <<= 1) { s1 += __shfl_xor(s1, o); s2 += __shfl_xor(s2, o); }
    int w = tid >> 6, l = tid & 63;
    if (l == 0) { rs1[w] = s1; rs2[w] = s2; }
    __syncthreads();
    float sum = rs1[0] + rs1[1], ssq = rs2[0] + rs2[1];
    float mu = sum * (1.f / 128.f);
    float var = ssq * (1.f / 128.f) - mu * mu;
    float rsig = rsqrtf(var + EPS);
    vn[tid] = (x - mu) * rsig * g_vd[tid] + b_vd[tid];
    __syncthreads();
    int n = tid & 63;
    if (tid < 64) {
        float acc = bq[n];
        for (int j = 0; j < 128; j++) acc += vn[j] * Wq[j * 64 + n];
        ws[8448 + blk * 64 + n] = fmaxf(acc, 0.f) * 0.35355339059327373f;
    } else {
        float acc = 0.f;
        for (int j = 0; j < 128; j++) acc += row[j] * We[(128 + j) * 64 + n];
        ws[73984 + blk * 64 + n] = acc;
    }
}

// one block per (b,s): stats of V_src row; Qs_k/Qs_v (g_in-folded) and Ps
__global__ __launch_bounds__(192) void src_kernel(const float* __restrict__ V_src,
                           const float* __restrict__ g_in,
                           const float* __restrict__ Wk, const float* __restrict__ Wv,
                           const float* __restrict__ We, float* __restrict__ ws) {
    int blk = blockIdx.x;           // b*256 + s
    int tid = threadIdx.x;          // 192
    __shared__ float row[128];
    if (tid < 128) row[tid] = V_src[blk * 128 + tid];
    __syncthreads();
    if (tid < 64) {
        float a = row[tid], b2 = row[tid + 64];
        float s1 = a + b2, s2 = a * a + b2 * b2;
        #pragma unroll
        for (int o = 1; o <= 32; o <<= 1) { s1 += __shfl_xor(s1, o); s2 += __shfl_xor(s2, o); }
        if (tid == 0) { ws[139520 + blk] = s1; ws[140544 + blk] = s2; }
    }
    int g = tid / 64, n = tid & 63;
    float acc = 0.f;
    if (g == 0) {
        for (int j = 0; j < 128; j++) acc += row[j] * g_in[j] * Wk[j * 64 + n];
        ws[141568 + blk * 64 + n] = acc;
    } else if (g == 1) {
        for (int j = 0; j < 128; j++) acc += row[j] * g_in[j] * Wv[j * 64 + n];
        ws[207104 + blk * 64 + n] = acc;
    } else {
        for (int j = 0; j < 128; j++) acc += row[j] * We[j * 64 + n];
        ws[272640 + blk * 64 + n] = acc;
    }
}

// one block (4 waves) per (b,d); each wave owns 64 s-values; lane n = (h=n/8, x=n%8)
__global__ __launch_bounds__(256) void attn_kernel(const float* __restrict__ E, const float* __restrict__ A,
                            const float* __restrict__ V_dst,
                            const float* __restrict__ Wo, const float* __restrict__ bo,
                            const float* __restrict__ ws, float* __restrict__ out0) {
    int blk = blockIdx.x;
    int b = blk >> 8, d = blk & 255;
    int tid = threadIdx.x, wv = tid >> 6, lane = tid & 63;
    float cK = ws[8192 + lane], dK = ws[8256 + lane];
    float cV = ws[8320 + lane], dV = ws[8384 + lane];
    float qs = ws[8448 + blk * 64 + lane];
    float wk[64], wvr[64];
    #pragma unroll
    for (int j = 0; j < 64; j++) { wk[j] = ws[j * 64 + lane]; wvr[j] = ws[4096 + j * 64 + lane]; }
    const float* sv  = ws + 139520 + b * 256;
    const float* ssv = ws + 140544 + b * 256;
    const float* Qsk = ws + 141568 + (size_t)b * 256 * 64;
    const float* Qsv = ws + 207104 + (size_t)b * 256 * 64;
    float o_acc = 0.f;
    for (int si = 0; si < 64; si++) {
        int s = wv * 64 + si;
        float a = A[(b * 256 + s) * 256 + d];
        float e = E[(size_t)(((b * 256 + s) * 256 + d)) * 64 + lane];
        float s1 = e, s2 = e * e;
        #pragma unroll
        for (int o = 1; o <= 32; o <<= 1) { s1 += __shfl_xor(s1, o); s2 += __shfl_xor(s2, o); }
        float mu  = (a * sv[s] + s1) * (1.f / 192.f);
        float ex2 = (a * a * ssv[s] + s2) * (1.f / 192.f);
        float rsig = rsqrtf(ex2 - mu * mu + EPS);
        float qek = 0.f, qev = 0.f;
        #pragma unroll
        for (int j = 0; j < 64; j++) {
            float eb = __shfl(e, j);
            qek += eb * wk[j];
            qev += eb * wvr[j];
        }
        float kk = fmaxf(rsig * (a * Qsk[s * 64 + lane] + qek) - rsig * mu * cK + dK, 0.f);
        float vl = fmaxf(rsig * (a * Qsv[s * 64 + lane] + qev) - rsig * mu * cV + dV, 0.f);
        float sc = qs * kk;                       // q pre-scaled by 1/sqrt(8)
        sc += __shfl_xor(sc, 1); sc += __shfl_xor(sc, 2); sc += __shfl_xor(sc, 4);  // per-head score
        float m = sc;
        m = fmaxf(m, __shfl_xor(m, 8)); m = fmaxf(m, __shfl_xor(m, 16)); m = fmaxf(m, __shfl_xor(m, 32));
        float p = __expf(sc - m);
        float den = p;
        den += __shfl_xor(den, 8); den += __shfl_xor(den, 16); den += __shfl_xor(den, 32);
        o_acc += (p / den) * vl;
    }
    __shared__ float osm[4][64];
    __shared__ float otot[64];
    osm[wv][lane] = o_acc;
    __syncthreads();
    if (tid < 64) otot[tid] = osm[0][tid] + osm[1][tid] + osm[2][tid] + osm[3][tid];
    __syncthreads();
    if (tid < 128) {
        float acc = bo[tid];
        for (int n = 0; n < 64; n++) acc += otot[n] * Wo[n * 128 + tid];
        out0[blk * 128 + tid] = V_dst[blk * 128 + tid] + fmaxf(acc, 0.f);
    }
}

// E_new = relu(A*(Ps+Pd) + E@We[256:320] + be); one wave per row, grid-stride
__global__ __launch_bounds__(256) void enew_kernel(const float* __restrict__ E, const float* __restrict__ A,
                            const float* __restrict__ We, const float* __restrict__ be,
                            const float* __restrict__ ws, float* __restrict__ out1) {
    int tid = threadIdx.x, wv = tid >> 6, lane = tid & 63;
    float we3[64];
    #pragma unroll
    for (int j = 0; j < 64; j++) we3[j] = We[(256 + j) * 64 + lane];
    float beL = be[lane];
    const float* Ps = ws + 272640;
    const float* Pd = ws + 73984;
    int wid = blockIdx.x * 4 + wv;   // 0..4095
    for (int r0 = 0; r0 < 64; r0++) {
        int r = wid + (r0 << 12);    // 0..262143
        int b = r >> 16, rem = r & 65535, s = rem >> 8, d = rem & 255;
        float e = E[(size_t)r * 64 + lane];
        float a = A[r];
        float pe = 0.f;
        #pragma unroll
        for (int j = 0; j < 64; j++) pe += __shfl(e, j) * we3[j];
        float ps = Ps[(b * 256 + s) * 64 + lane];
        float pd = Pd[(b * 256 + d) * 64 + lane];
        out1[(size_t)r * 64 + lane] = fmaxf(a * (ps + pd) + pe + beL, 0.f);
    }
}

// A_new = softmax over singleton axis == exactly 1.0
__global__ __launch_bounds__(256) void ones_kernel(float* __restrict__ out2) {
    int idx = blockIdx.x * 256 + threadIdx.x;
    out2[idx] = 1.0f;   // grid 1024*256 == 262144 exactly
}

extern "C" void kernel_launch(void* const* d_in, const int* in_sizes, int n_in,
                              void* d_out, int out_size, void* d_ws, size_t ws_size,
                              hipStream_t stream) {
    (void)in_sizes; (void)n_in; (void)out_size; (void)ws_size;
    const float* V_src = (const float*)d_in[0];
    const float* V_dst = (const float*)d_in[1];
    const float* E     = (const float*)d_in[2];
    const float* A     = (const float*)d_in[3];
    const float* g_vd  = (const float*)d_in[4];
    const float* b_vd  = (const float*)d_in[5];
    const float* g_in  = (const float*)d_in[6];
    const float* b_in  = (const float*)d_in[7];
    const float* Wq    = (const float*)d_in[8];
    const float* bq    = (const float*)d_in[9];
    const float* Wk    = (const float*)d_in[10];
    const float* bk    = (const float*)d_in[11];
    const float* Wv    = (const float*)d_in[12];
    const float* bv    = (const float*)d_in[13];
    const float* Wo    = (const float*)d_in[14];
    const float* bo    = (const float*)d_in[15];
    const float* We    = (const float*)d_in[16];
    const float* be    = (const float*)d_in[17];
    float* ws   = (float*)d_ws;
    float* out0 = (float*)d_out;
    float* out1 = out0 + 131072;            // E_new [B,S,D,64]
    float* out2 = out1 + 16777216;          // A_new [B,S,D]

    hipLaunchKernelGGL(prep_kernel, dim3(1),    dim3(256), 0, stream, Wk, bk, Wv, bv, g_in, b_in, ws);
    hipLaunchKernelGGL(dst_kernel,  dim3(1024), dim3(128), 0, stream, V_dst, g_vd, b_vd, Wq, bq, We, ws);
    hipLaunchKernelGGL(src_kernel,  dim3(1024), dim3(192), 0, stream, V_src, g_in, Wk, Wv, We, ws);
    hipLaunchKernelGGL(attn_kernel, dim3(1024), dim3(256), 0, stream, E, A, V_dst, Wo, bo, ws, out0);
    hipLaunchKernelGGL(enew_kernel, dim3(1024), dim3(256), 0, stream, E, A, We, be, ws, out1);
    hipLaunchKernelGGL(ones_kernel, dim3(1024), dim3(256), 0, stream, out2);
}

// Round 2
// 285.476 us; speedup vs baseline: 2.7279x; 2.7279x over previous
//
#include <hip/hip_runtime.h>
#include <hip/hip_bf16.h>
#include <math.h>

#define EPS 1e-3f
// B=4, S=256, D=256, v=128, e=64, c=192, NH=8, DK=8, DV=8

// ws layout (floats):
// 8192   : cK[64], 8256: dK[64], 8320: cV[64], 8384: dV[64]
// 8448   : q_s [B*D*64]  (relu(q)/sqrt(8))
// 73984  : Pd  [B*D*64]  (V_dst @ We[128:256])
// 139520 : sv  [B*S]     (sum of V_src row)
// 140544 : ssv [B*S]     (sumsq of V_src row)
// 141568 : Qs_k[B*S*64]  (g_in-folded V_src @ Wk[0:128])
// 207104 : Qs_v[B*S*64]
// 272640 : Ps  [B*S*64]  (V_src @ We[0:128])
// 338176 : Wcat bf16 [192 n][64 k]  = [g_in*WkE | g_in*WvE | We3]  (12288 ushort)
#define WCAT_OFF 338176

typedef __attribute__((ext_vector_type(8))) short short8;
typedef __attribute__((ext_vector_type(8))) unsigned short ushort8;
typedef __attribute__((ext_vector_type(4))) float floatx4;

__device__ __forceinline__ unsigned short f2bf(float f) {
    __hip_bfloat16 h = __float2bfloat16(f);
    return *reinterpret_cast<unsigned short*>(&h);
}

__global__ void prep_kernel(const float* __restrict__ Wk, const float* __restrict__ bk,
                            const float* __restrict__ Wv, const float* __restrict__ bv,
                            const float* __restrict__ g_in, const float* __restrict__ b_in,
                            const float* __restrict__ We, float* __restrict__ ws) {
    int tid = threadIdx.x;
    int n = tid & 63;
    if (tid < 64) {
        float c = 0.f, dd = 0.f;
        for (int j = 0; j < 192; j++) { float w = Wk[j * 64 + n]; c += g_in[j] * w; dd += b_in[j] * w; }
        ws[8192 + n] = c; ws[8256 + n] = dd + bk[n];
    } else if (tid < 128) {
        float c = 0.f, dd = 0.f;
        for (int j = 0; j < 192; j++) { float w = Wv[j * 64 + n]; c += g_in[j] * w; dd += b_in[j] * w; }
        ws[8320 + n] = c; ws[8384 + n] = dd + bv[n];
    }
    // Wcat bf16: [n][k], n<64 -> g_in[128+k]*Wk[(128+k)*64+n]; n<128 -> Wv; else We[256+k][n-128]
    unsigned short* wcat = (unsigned short*)(ws + WCAT_OFF);
    for (int idx = tid; idx < 12288; idx += 256) {
        int nn = idx >> 6, k = idx & 63;
        float w;
        if (nn < 64)       w = g_in[128 + k] * Wk[(128 + k) * 64 + nn];
        else if (nn < 128) w = g_in[128 + k] * Wv[(128 + k) * 64 + (nn - 64)];
        else               w = We[(256 + k) * 64 + (nn - 128)];
        wcat[idx] = f2bf(w);
    }
}

// one block per (b,d): LN(V_dst) -> q (pre-scaled by 1/sqrt(8)); Pd = V_dst @ We[128:256]
__global__ __launch_bounds__(128) void dst_kernel(const float* __restrict__ V_dst,
                           const float* __restrict__ g_vd, const float* __restrict__ b_vd,
                           const float* __restrict__ Wq, const float* __restrict__ bq,
                           const float* __restrict__ We, float* __restrict__ ws) {
    int blk = blockIdx.x;           // b*256 + d
    int tid = threadIdx.x;          // 128
    __shared__ float row[128], vn[128], rs1[2], rs2[2];
    float x = V_dst[blk * 128 + tid];
    row[tid] = x;
    float s1 = x, s2 = x * x;
    #pragma unroll
    for (int o = 1; o <= 32; o <<= 1) { s1 += __shfl_xor(s1, o); s2 += __shfl_xor(s2, o); }
    int w = tid >> 6, l = tid & 63;
    if (l == 0) { rs1[w] = s1; rs2[w] = s2; }
    __syncthreads();
    float sum = rs1[0] + rs1[1], ssq = rs2[0] + rs2[1];
    float mu = sum * (1.f / 128.f);
    float var = ssq * (1.f / 128.f) - mu * mu;
    float rsig = rsqrtf(var + EPS);
    vn[tid] = (x - mu) * rsig * g_vd[tid] + b_vd[tid];
    __syncthreads();
    int n = tid & 63;
    if (tid < 64) {
        float acc = bq[n];
        for (int j = 0; j < 128; j++) acc += vn[j] * Wq[j * 64 + n];
        ws[8448 + blk * 64 + n] = fmaxf(acc, 0.f) * 0.35355339059327373f;
    } else {
        float acc = 0.f;
        for (int j = 0; j < 128; j++) acc += row[j] * We[(128 + j) * 64 + n];
        ws[73984 + blk * 64 + n] = acc;
    }
}

// one block per (b,s): stats of V_src row; Qs_k/Qs_v (g_in-folded) and Ps
__global__ __launch_bounds__(192) void src_kernel(const float* __restrict__ V_src,
                           const float* __restrict__ g_in,
                           const float* __restrict__ Wk, const float* __restrict__ Wv,
                           const float* __restrict__ We, float* __restrict__ ws) {
    int blk = blockIdx.x;           // b*256 + s
    int tid = threadIdx.x;          // 192
    __shared__ float row[128];
    if (tid < 128) row[tid] = V_src[blk * 128 + tid];
    __syncthreads();
    if (tid < 64) {
        float a = row[tid], b2 = row[tid + 64];
        float s1 = a + b2, s2 = a * a + b2 * b2;
        #pragma unroll
        for (int o = 1; o <= 32; o <<= 1) { s1 += __shfl_xor(s1, o); s2 += __shfl_xor(s2, o); }
        if (tid == 0) { ws[139520 + blk] = s1; ws[140544 + blk] = s2; }
    }
    int g = tid / 64, n = tid & 63;
    float acc = 0.f;
    if (g == 0) {
        for (int j = 0; j < 128; j++) acc += row[j] * g_in[j] * Wk[j * 64 + n];
        ws[141568 + blk * 64 + n] = acc;
    } else if (g == 1) {
        for (int j = 0; j < 128; j++) acc += row[j] * g_in[j] * Wv[j * 64 + n];
        ws[207104 + blk * 64 + n] = acc;
    } else {
        for (int j = 0; j < 128; j++) acc += row[j] * We[j * 64 + n];
        ws[272640 + blk * 64 + n] = acc;
    }
}

// Fused: per (b,d) block. Stage E rows bf16 -> MFMA (qek|qev|pe) -> per-row
// softmax-over-heads epilogue + E_new + A_new writes + attention out.
// All main-loop LDS traffic is wave-local: no __syncthreads until epilogue.
__global__ __launch_bounds__(256, 2) void fused_kernel(
        const float* __restrict__ E, const float* __restrict__ A,
        const float* __restrict__ V_dst,
        const float* __restrict__ Wo, const float* __restrict__ bo,
        const float* __restrict__ be,
        const float* __restrict__ ws,
        float* __restrict__ out0, float* __restrict__ out1, float* __restrict__ out2) {
    int blk = blockIdx.x;
    int b = blk >> 8, d = blk & 255;
    int tid = threadIdx.x, wv = tid >> 6, lane = tid & 63;
    int col = lane & 15, quad = lane >> 4;

    __shared__ unsigned short Ebf[64 * 72];   // 64 rows x 64 bf16, stride 72 (pad)
    __shared__ float res[64 * 196];           // 64 rows x 192 fp32, stride 196 (pad)
    __shared__ float ssum[64], sssq[64];
    __shared__ float osm[4][64];
    __shared__ float otot[64];

    float cK = ws[8192 + lane], dK = ws[8256 + lane];
    float cV = ws[8320 + lane], dV = ws[8384 + lane];
    float qs  = ws[8448 + blk * 64 + lane];
    float pdv = ws[73984 + blk * 64 + lane];
    float beL = be[lane];
    const float* sv  = ws + 139520 + b * 256;
    const float* ssv = ws + 140544 + b * 256;
    const float* Qsk = ws + 141568 + (size_t)b * 16384;
    const float* Qsv = ws + 207104 + (size_t)b * 16384;
    const float* Ps  = ws + 272640 + (size_t)b * 16384;
    const unsigned short* Wcat = (const unsigned short*)(ws + WCAT_OFF);

    // preload B-fragments: 12 N-tiles x 2 K-chunks, resident in VGPRs
    short8 bfrag[24];
    #pragma unroll
    for (int t = 0; t < 12; t++) {
        #pragma unroll
        for (int c = 0; c < 2; c++)
            bfrag[t * 2 + c] = *(const short8*)(Wcat + ((t * 16 + col) * 64 + c * 32 + quad * 8));
    }

    float o_acc = 0.f;
    int rstage = tid >> 2, gstage = tid & 3;   // staging: 4 threads per row

    for (int chunk = 0; chunk < 4; chunk++) {
        int s0 = chunk * 64;
        // ---- stage 64 rows of E (fp32 -> bf16) + exact fp32 row stats ----
        {
            const float* ep = E + ((size_t)(((b * 256 + s0 + rstage) * 256 + d))) * 64 + gstage * 16;
            float4 e0 = *(const float4*)(ep);
            float4 e1 = *(const float4*)(ep + 4);
            float4 e2 = *(const float4*)(ep + 8);
            float4 e3 = *(const float4*)(ep + 12);
            float s1 = (e0.x + e0.y + e0.z + e0.w) + (e1.x + e1.y + e1.z + e1.w)
                     + (e2.x + e2.y + e2.z + e2.w) + (e3.x + e3.y + e3.z + e3.w);
            float s2 = (e0.x*e0.x + e0.y*e0.y + e0.z*e0.z + e0.w*e0.w)
                     + (e1.x*e1.x + e1.y*e1.y + e1.z*e1.z + e1.w*e1.w)
                     + (e2.x*e2.x + e2.y*e2.y + e2.z*e2.z + e2.w*e2.w)
                     + (e3.x*e3.x + e3.y*e3.y + e3.z*e3.z + e3.w*e3.w);
            s1 += __shfl_xor(s1, 1); s2 += __shfl_xor(s2, 1);
            s1 += __shfl_xor(s1, 2); s2 += __shfl_xor(s2, 2);
            if (gstage == 0) { ssum[rstage] = s1; sssq[rstage] = s2; }
            ushort8 w0, w1;
            w0[0]=f2bf(e0.x); w0[1]=f2bf(e0.y); w0[2]=f2bf(e0.z); w0[3]=f2bf(e0.w);
            w0[4]=f2bf(e1.x); w0[5]=f2bf(e1.y); w0[6]=f2bf(e1.z); w0[7]=f2bf(e1.w);
            w1[0]=f2bf(e2.x); w1[1]=f2bf(e2.y); w1[2]=f2bf(e2.z); w1[3]=f2bf(e2.w);
            w1[4]=f2bf(e3.x); w1[5]=f2bf(e3.y); w1[6]=f2bf(e3.z); w1[7]=f2bf(e3.w);
            *(ushort8*)(Ebf + rstage * 72 + gstage * 16)     = w0;
            *(ushort8*)(Ebf + rstage * 72 + gstage * 16 + 8) = w1;
        }
        // ---- MFMA: wave wv computes its 16 rows x 192 cols (wave-local) ----
        {
            short8 a0 = *(const short8*)(Ebf + (wv * 16 + col) * 72 + quad * 8);
            short8 a1 = *(const short8*)(Ebf + (wv * 16 + col) * 72 + 32 + quad * 8);
            #pragma unroll
            for (int t = 0; t < 12; t++) {
                floatx4 acc = {0.f, 0.f, 0.f, 0.f};
                acc = __builtin_amdgcn_mfma_f32_16x16x32_bf16(a0, bfrag[2 * t],     acc, 0, 0, 0);
                acc = __builtin_amdgcn_mfma_f32_16x16x32_bf16(a1, bfrag[2 * t + 1], acc, 0, 0, 0);
                #pragma unroll
                for (int r = 0; r < 4; r++)
                    res[(wv * 16 + quad * 4 + r) * 196 + t * 16 + col] = acc[r];
            }
        }
        // ---- per-row epilogue: softmax over heads + E_new + A_new (wave-local) ----
        for (int i = 0; i < 16; i++) {
            int sl = wv * 16 + i;
            int s = s0 + sl;
            int row = (b * 256 + s) * 256 + d;
            float a = A[row];
            float qek = res[sl * 196 + lane];
            float qev = res[sl * 196 + 64 + lane];
            float pe  = res[sl * 196 + 128 + lane];
            float mu  = (a * sv[s] + ssum[sl]) * (1.f / 192.f);
            float ex2 = (a * a * ssv[s] + sssq[sl]) * (1.f / 192.f);
            float rsig = rsqrtf(ex2 - mu * mu + EPS);
            float kk = fmaxf(rsig * (a * Qsk[s * 64 + lane] + qek) - rsig * mu * cK + dK, 0.f);
            float vl = fmaxf(rsig * (a * Qsv[s * 64 + lane] + qev) - rsig * mu * cV + dV, 0.f);
            float sc = qs * kk;                       // q pre-scaled by 1/sqrt(8)
            sc += __shfl_xor(sc, 1); sc += __shfl_xor(sc, 2); sc += __shfl_xor(sc, 4);
            float m = sc;
            m = fmaxf(m, __shfl_xor(m, 8)); m = fmaxf(m, __shfl_xor(m, 16)); m = fmaxf(m, __shfl_xor(m, 32));
            float p = __expf(sc - m);
            float den = p;
            den += __shfl_xor(den, 8); den += __shfl_xor(den, 16); den += __shfl_xor(den, 32);
            o_acc += (p / den) * vl;
            out1[(size_t)row * 64 + lane] = fmaxf(a * (Ps[s * 64 + lane] + pdv) + pe + beL, 0.f);
            if (lane == 0) out2[row] = 1.0f;
        }
    }
    // ---- cross-wave o reduction + Wo epilogue ----
    osm[wv][lane] = o_acc;
    __syncthreads();
    if (tid < 64) otot[tid] = osm[0][tid] + osm[1][tid] + osm[2][tid] + osm[3][tid];
    __syncthreads();
    if (tid < 128) {
        float acc = bo[tid];
        for (int n = 0; n < 64; n++) acc += otot[n] * Wo[n * 128 + tid];
        out0[blk * 128 + tid] = V_dst[blk * 128 + tid] + fmaxf(acc, 0.f);
    }
}

extern "C" void kernel_launch(void* const* d_in, const int* in_sizes, int n_in,
                              void* d_out, int out_size, void* d_ws, size_t ws_size,
                              hipStream_t stream) {
    (void)in_sizes; (void)n_in; (void)out_size; (void)ws_size;
    const float* V_src = (const float*)d_in[0];
    const float* V_dst = (const float*)d_in[1];
    const float* E     = (const float*)d_in[2];
    const float* A     = (const float*)d_in[3];
    const float* g_vd  = (const float*)d_in[4];
    const float* b_vd  = (const float*)d_in[5];
    const float* g_in  = (const float*)d_in[6];
    const float* b_in  = (const float*)d_in[7];
    const float* Wq    = (const float*)d_in[8];
    const float* bq    = (const float*)d_in[9];
    const float* Wk    = (const float*)d_in[10];
    const float* bk    = (const float*)d_in[11];
    const float* Wv    = (const float*)d_in[12];
    const float* bv    = (const float*)d_in[13];
    const float* Wo    = (const float*)d_in[14];
    const float* bo    = (const float*)d_in[15];
    const float* We    = (const float*)d_in[16];
    const float* be    = (const float*)d_in[17];
    float* ws   = (float*)d_ws;
    float* out0 = (float*)d_out;
    float* out1 = out0 + 131072;            // E_new [B,S,D,64]
    float* out2 = out1 + 16777216;          // A_new [B,S,D]

    hipLaunchKernelGGL(prep_kernel,  dim3(1),    dim3(256), 0, stream, Wk, bk, Wv, bv, g_in, b_in, We, ws);
    hipLaunchKernelGGL(dst_kernel,   dim3(1024), dim3(128), 0, stream, V_dst, g_vd, b_vd, Wq, bq, We, ws);
    hipLaunchKernelGGL(src_kernel,   dim3(1024), dim3(192), 0, stream, V_src, g_in, Wk, Wv, We, ws);
    hipLaunchKernelGGL(fused_kernel, dim3(1024), dim3(256), 0, stream, E, A, V_dst, Wo, bo, be, ws, out0, out1, out2);
}